// Round 7
// baseline (310.987 us; speedup 1.0000x reference)
//
#include <hip/hip_runtime.h>
#include <stdint.h>

#define T_LEN 1460
#define NBT (256 * T_LEN)          // 373,760 (b,t) records
#define NREC (NBT * 16)            // 5,980,160 chain records
#define RSLOT 2304                 // ring slot bytes: 1024 (partA) + 1024 (partB) + 256 (V)
#define NRING 16

typedef __attribute__((address_space(3))) char lds_c;
typedef __attribute__((address_space(1))) const char g_c;

__device__ __forceinline__ float sigmf(float x) {
    float e = __builtin_amdgcn_exp2f(-1.44269504f * x);
    return __builtin_amdgcn_rcpf(1.0f + e);
}
__device__ __forceinline__ float rcpf(float x) { return __builtin_amdgcn_rcpf(x); }

// sum over each 16-lane row via full-rate DPP adds; result broadcast to all 16
__device__ __forceinline__ float row_sum16(float x) {
    x += __int_as_float(__builtin_amdgcn_update_dpp(0, __float_as_int(x), 0xB1, 0xF, 0xF, true));
    x += __int_as_float(__builtin_amdgcn_update_dpp(0, __float_as_int(x), 0x4E, 0xF, 0xF, true));
    x += __int_as_float(__builtin_amdgcn_update_dpp(0, __float_as_int(x), 0x141, 0xF, 0xF, true));
    x += __int_as_float(__builtin_amdgcn_update_dpp(0, __float_as_int(x), 0x140, 0xF, 0xF, true));
    return x;
}

// ---------------------------------------------------------------------------
// Kernel A (unchanged from round 4, proven): pointwise parameter mapping.
// R record per (b,t,m): {sm, f_thr, sumax, beta | perc, 1/kf, 1/ki, 1/kb}.
// V per (b,t): {sn, lpq, 0.9*pet, 0}.
// ---------------------------------------------------------------------------
__global__ __launch_bounds__(256) void shm_param_kernel(
    const float* __restrict__ xc, const float* __restrict__ lo,
    float* __restrict__ R, float* __restrict__ V)
{
    const int tid = blockIdx.x * 256 + threadIdx.x;
    const int m  = tid & 15;
    const int bt = tid >> 4;

    const float* lr = lo + (size_t)bt * 128 + m;
    const float r0 = lr[0],   r1 = lr[16],  r2 = lr[32],  r3 = lr[48];
    const float r4 = lr[64],  r5 = lr[80],  r6 = lr[96],  r7 = lr[112];

    const float* xp = xc + (size_t)bt * 3;
    const float prec = xp[0], pet = xp[1], temp = xp[2];
    const bool frozen = (temp < 0.f);
    const float tpos = frozen ? 0.f : temp;

    const float dd    = 10.f * sigmf(r0);
    const float sm    = tpos * dd;
    const float f_thr = fmaf(sigmf(r1), 50.f, 10.f);
    const float sumax = fmaf(sigmf(r2), 680.f, 20.f);
    const float beta  = fmaf(sigmf(r3), 5.f, 1.f);
    const float perc  = sigmf(r4);
    const float rkf   = rcpf(fmaf(sigmf(r5), 19.f, 1.f));
    const float rki   = rcpf(fmaf(sigmf(r6), 99.f, 1.f));
    const float rkb   = rcpf(fmaf(sigmf(r7), 990.f, 10.f));

    float4* Rp = (float4*)(R + (size_t)tid * 8);
    Rp[0] = make_float4(sm, f_thr, sumax, beta);
    Rp[1] = make_float4(perc, rkf, rki, rkb);
    if (m == 0)
        *(float4*)(V + (size_t)bt * 4) =
            make_float4(frozen ? prec : 0.f, frozen ? 0.f : prec, 0.9f * pet, 0.f);
}

// ---------------------------------------------------------------------------
// Kernel B: serial scan with a 16-slot LDS ring fed by global_load_lds DMA.
// No register-destination loads in flight; counted vmcnt(39) per step.
// ---------------------------------------------------------------------------
__global__ __launch_bounds__(64, 1) void shm_serial_kernel(
    const float* __restrict__ R,
    const float* __restrict__ V,
    float* __restrict__ out)
{
    __shared__ __align__(16) char ring[NRING * RSLOT];   // 36,864 B
    lds_c* ringc = (lds_c*)ring;
    const uint32_t ringB = (uint32_t)(uintptr_t)ringc;

    const int lane = threadIdx.x;
    const int m = lane & 15;
    const int b = (blockIdx.x * 64 + lane) >> 4;

    const float* baseR = R + ((size_t)b * T_LEN * 16 + m) * 8;  // +128 floats/step
    const float* baseV = V + (size_t)b * T_LEN * 4;             // +4 floats/step
    float* op = out + (size_t)b * T_LEN;

    float ss = 0.f, sf = 1.f, su = 5.f, si = 10.f, sb = 15.f;
    float qkeep = 0.f;

#define DMA16(gp, off) __builtin_amdgcn_global_load_lds((g_c*)(gp), ringc + (off), 16, 0, 0)
#define DMA4(gp, off)  __builtin_amdgcn_global_load_lds((g_c*)(gp), ringc + (off), 4, 0, 0)

#define ISSUE(tt) {                                                          \
    const int sd_ = (tt) & 15;                                               \
    const float* gp_ = baseR + (size_t)(tt) * 128;                           \
    const float* gv_ = baseV + (size_t)(tt) * 4 + (lane & 3);                \
    DMA16(gp_,     sd_ * RSLOT);                                             \
    DMA16(gp_ + 4, sd_ * RSLOT + 1024);                                      \
    DMA4 (gv_,     sd_ * RSLOT + 2048);                                      \
}

#define READSLOT(ss_, DA, DB, DV) {                                          \
    uint32_t a_p = ringB + (ss_) * RSLOT + lane * 16;                        \
    uint32_t a_v = ringB + (ss_) * RSLOT + 2048 + ((lane & ~3) << 2);        \
    asm volatile("ds_read_b128 %0, %3\n\t"                                   \
                 "ds_read_b128 %1, %3 offset:1024\n\t"                       \
                 "ds_read_b128 %2, %4"                                       \
                 : "=&v"(DA), "=&v"(DB), "=&v"(DV)                           \
                 : "v"(a_p), "v"(a_v));                                      \
}

#define STEPC(Af, Bf, Vf, tt) {                                              \
    const float smv = Af.x, f_thr = Af.y, sumax = Af.z, beta = Af.w;         \
    const float perc = Bf.x, rkf = Bf.y, rki = Bf.z, rkb = Bf.w;             \
    const float et09 = Vf.z;                                                 \
    const float inv = rcpf(sumax);                                           \
    const float pwp = 0.8f * sumax;                                          \
    const float e_i = et09 * inv;                                            \
    const float qs_out = fminf(ss, smv);                                     \
    ss = (ss - qs_out) + Vf.x;                                               \
    const float qsp = qs_out + Vf.y;                                         \
    const float qf_in = fmaxf(0.f, qsp - f_thr);                             \
    const float qu_in = fminf(qsp, f_thr);                                   \
    sf += qf_in; const float qf_out = sf * rkf; sf -= qf_out;                \
    const float u = su * inv;                                                \
    const float psi = __builtin_amdgcn_exp2f(beta * __builtin_amdgcn_logf(u)); \
    const float su_t = fmaf(qu_in, 1.f - psi, su);                           \
    const float su2 = fminf(su_t, sumax);                                    \
    const float ovf = fmaxf(0.f, su_t - sumax);                              \
    const float qu_out = fmaf(qu_in, psi, ovf);                              \
    const float ret = (su2 <= pwp) ? su2 * e_i : et09;                       \
    su = fmaxf(0.f, su2 - ret);                                              \
    const float qi_in = qu_out * perc;                                       \
    si += qi_in; const float qi_out = si * rki; si -= qi_out;                \
    const float qb_in = qu_out - qi_in;                                      \
    sb += qb_in; const float qb_out = sb * rkb; sb -= qb_out;                \
    const float q = row_sum16(qf_out + qi_out + qb_out) * 0.0625f;           \
    qkeep = (m == ((tt) & 15)) ? q : qkeep;                                  \
    if (((tt) & 15) == 15) op[((tt) & ~15) + m] = qkeep;                     \
}

#define ITER(tt, CA, CB, CV, NA, NB, NV) {                                   \
    asm volatile("s_waitcnt vmcnt(39)" ::: "memory");                        \
    __builtin_amdgcn_sched_barrier(0);                                       \
    READSLOT(((tt) + 1) & 15, NA, NB, NV);                                   \
    if ((tt) <= T_LEN - 16) ISSUE((tt) + 15);                                \
    STEPC(CA, CB, CV, (tt));                                                 \
    asm volatile("s_waitcnt lgkmcnt(0)" ::: "memory");                       \
    __builtin_amdgcn_sched_barrier(0);                                       \
}

    float4 XA, XB, XV, YA, YB, YV;

    // prologue: DMA slots 0..14 (45 vmcnt entries)
    for (int j = 0; j < 15; ++j) ISSUE(j);
    asm volatile("s_waitcnt vmcnt(42)" ::: "memory");   // slot 0 arrived
    __builtin_amdgcn_sched_barrier(0);
    READSLOT(0, XA, XB, XV);
    asm volatile("s_waitcnt lgkmcnt(0)" ::: "memory");
    __builtin_amdgcn_sched_barrier(0);

    // main loop: t = 0..1445 (even count, unroll 2 with X/Y role swap)
    for (int tp = 0; tp < 1446; tp += 2) {
        ITER(tp,     XA, XB, XV, YA, YB, YV);
        ITER(tp + 1, YA, YB, YV, XA, XB, XV);
    }

    // tail: t = 1446..1459 — everything already DMA'd; drain and go plain
    asm volatile("s_waitcnt vmcnt(0)" ::: "memory");
    __builtin_amdgcn_sched_barrier(0);
    for (int t = 1446; t < T_LEN; ++t) {
        float4 TA, TB, TV;
        READSLOT(t & 15, TA, TB, TV);
        asm volatile("s_waitcnt lgkmcnt(0)" ::: "memory");
        __builtin_amdgcn_sched_barrier(0);
        STEPC(TA, TB, TV, t);
    }
    if (m < 4) op[1456 + m] = qkeep;   // t = 1456..1459 (KC = 0..3)

#undef DMA16
#undef DMA4
#undef ISSUE
#undef READSLOT
#undef STEPC
#undef ITER
}

// ---------------------------------------------------------------------------
// Fallback (proven round-2 kernel) if ws_size is too small.
// ---------------------------------------------------------------------------
#define CS 10
#define NCHUNK 146
#define IST 66

__device__ __forceinline__ float lane0f(float x) {
    return __int_as_float(__builtin_amdgcn_readlane(__float_as_int(x), 0));
}

__global__ __launch_bounds__(256, 1) void shm_pc_kernel(
    const float* __restrict__ xc, const float* __restrict__ lo,
    float* __restrict__ out)
{
    __shared__ float pbuf[2][CS][8][IST];
    __shared__ float bbuf[2][CS][4][4];

    const int lane  = threadIdx.x & 63;
    const int wid   = threadIdx.x >> 6;
    const int bbase = blockIdx.x * 4;

    const int ip = lane >> 3;
    const float A  = (ip==1)?10.f : (ip==2)?20.f : (ip==3)?1.f :
                     (ip==5)?1.f  : (ip==6)?1.f  : (ip==7)?10.f : 0.f;
    const float Bc = (ip==0)?10.f : (ip==1)?50.f : (ip==2)?680.f : (ip==3)?5.f :
                     (ip==4)?1.f  : (ip==5)?19.f : (ip==6)?99.f  : 990.f;
    const bool drcp = (ip >= 5);
    const bool dsm  = (ip == 0);
    const int  mm   = (2*lane) & 15;

    auto produce = [&](int cc, int buf) {
        const int t0 = cc * CS;
        float2 raw[14];
        float xr0[14], xr1[14], xr2[14];
#pragma unroll
        for (int r = 0; r < 14; ++r) {
            const int tau = (wid - 1) + 3 * r;
            if (tau < 40) {
                const int g  = tau / CS;
                const int tl = tau - g * CS;
                const size_t rowoff = (size_t)(bbase + g) * T_LEN + (t0 + tl);
                raw[r] = *(const float2*)(lo + rowoff * 128 + 2 * lane);
                if (lane == 0) {
                    const float* xp = xc + rowoff * 3;
                    xr0[r] = xp[0]; xr1[r] = xp[1]; xr2[r] = xp[2];
                }
            }
        }
#pragma unroll
        for (int r = 0; r < 14; ++r) {
            const int tau = (wid - 1) + 3 * r;
            if (tau < 40) {
                const int g  = tau / CS;
                const int tl = tau - g * CS;
                const float prec = lane0f(xr0[r]);
                const float pet  = lane0f(xr1[r]);
                const float temp = lane0f(xr2[r]);
                const bool frozen = (temp < 0.f);
                const float tpos = frozen ? 0.f : temp;
                const float sn   = frozen ? prec : 0.f;
                const float lpq  = frozen ? 0.f : prec;
                const float et09 = 0.9f * pet;

                float v0 = fmaf(sigmf(raw[r].x), Bc, A);
                float v1 = fmaf(sigmf(raw[r].y), Bc, A);
                v0 = drcp ? rcpf(v0) : v0;
                v1 = drcp ? rcpf(v1) : v1;
                v0 = dsm ? v0 * tpos : v0;
                v1 = dsm ? v1 * tpos : v1;

                float* dst = &pbuf[buf][tl][ip][g * 16 + mm];
                *(float2*)dst = make_float2(v0, v1);
                if (lane == 0)
                    *(float4*)&bbuf[buf][tl][g][0] = make_float4(sn, lpq, et09, 0.f);
            }
        }
    };

    const int g = lane >> 4, m = lane & 15;
    float ss = 0.f, sf = 1.f, su = 5.f, si = 10.f, sb = 15.f;
    float* op = out + (size_t)(bbase + g) * T_LEN;

    if (wid != 0) produce(0, 0);
    __syncthreads();

    for (int c = 0; c < NCHUNK; ++c) {
        if (wid == 0) {
            const int buf = c & 1;
#pragma unroll
            for (int tl = 0; tl < CS; ++tl) {
                const float* rec = &pbuf[buf][tl][0][lane];
                const float sm    = rec[0 * IST];
                const float f_thr = rec[1 * IST];
                const float sumax = rec[2 * IST];
                const float beta  = rec[3 * IST];
                const float perc  = rec[4 * IST];
                const float rkf   = rec[5 * IST];
                const float rki   = rec[6 * IST];
                const float rkb   = rec[7 * IST];
                const float4 bx = *(const float4*)&bbuf[buf][tl][g][0];

                float qs_out = fminf(ss, sm);
                ss = ss - qs_out + bx.x;
                float qsp = qs_out + bx.y;
                float qf_in = fmaxf(0.f, qsp - f_thr);
                float qu_in = fminf(qsp, f_thr);
                sf += qf_in;
                float qf_out = sf * rkf;
                sf -= qf_out;
                float inv_sumax = rcpf(sumax);
                float u = su * inv_sumax;
                float psi = __builtin_amdgcn_exp2f(beta * __builtin_amdgcn_logf(u));
                float su_temp = fmaf(qu_in, 1.f - psi, su);
                su = fminf(su_temp, sumax);
                float ovf = fmaxf(0.f, su_temp - sumax);
                float qu_out = fmaf(qu_in, psi, ovf);
                float pwp = 0.8f * sumax;
                float ktheta = (su <= pwp) ? su * inv_sumax : 1.f;
                float ret = bx.z * ktheta;
                su = fmaxf(0.f, su - ret);
                float qi_in = qu_out * perc;
                si += qi_in;
                float qi_out = si * rki;
                si -= qi_out;
                float qb_in = qu_out - qi_in;
                sb += qb_in;
                float qb_out = sb * rkb;
                sb -= qb_out;

                float q = row_sum16(qf_out + qi_out + qb_out) * 0.0625f;
                if (m == 0) op[c * CS + tl] = q;
            }
        } else if (c + 1 < NCHUNK) {
            produce(c + 1, (c + 1) & 1);
        }
        __syncthreads();
    }
}

extern "C" void kernel_launch(void* const* d_in, const int* in_sizes, int n_in,
                              void* d_out, int out_size, void* d_ws, size_t ws_size,
                              hipStream_t stream) {
    const float* xc = (const float*)d_in[0];   // [256,1460,3]
    const float* lo = (const float*)d_in[1];   // [256,1460,128]
    float* out = (float*)d_out;                // [256,1460,1]

    const size_t R_BYTES = (size_t)NREC * 32;  // 191,365,120
    const size_t V_BYTES = (size_t)NBT * 16;   //   5,980,160

    if (ws_size >= R_BYTES + V_BYTES) {
        float* R = (float*)d_ws;
        float* V = (float*)((char*)d_ws + R_BYTES);
        shm_param_kernel<<<dim3(NREC / 256), dim3(256), 0, stream>>>(xc, lo, R, V);
        shm_serial_kernel<<<dim3(64), dim3(64), 0, stream>>>(R, V, out);
    } else {
        shm_pc_kernel<<<dim3(64), dim3(256), 0, stream>>>(xc, lo, out);
    }
}

// Round 11
// 288.428 us; speedup vs baseline: 1.0782x; 1.0782x over previous
//
#include <hip/hip_runtime.h>
#include <stdint.h>

#define T_LEN 1460
#define NBT (256 * T_LEN)          // 373,760 (b,t) records
#define NREC (NBT * 16)            // 5,980,160 chain records
#define RSLOT 2304                 // ring slot: 1024 (A) + 1024 (B) + 256 (V)
#define NRING 16
#define RINGSZ (NRING * RSLOT)     // 36864

typedef __attribute__((address_space(3))) char lds_c;
typedef __attribute__((address_space(1))) const char g_c;

__device__ __forceinline__ float sigmf(float x) {
    float e = __builtin_amdgcn_exp2f(-1.44269504f * x);
    return __builtin_amdgcn_rcpf(1.0f + e);
}
__device__ __forceinline__ float rcpf(float x) { return __builtin_amdgcn_rcpf(x); }

// sum over each 16-lane row via full-rate DPP adds; result broadcast to all 16
__device__ __forceinline__ float row_sum16(float x) {
    x += __int_as_float(__builtin_amdgcn_update_dpp(0, __float_as_int(x), 0xB1, 0xF, 0xF, true));
    x += __int_as_float(__builtin_amdgcn_update_dpp(0, __float_as_int(x), 0x4E, 0xF, 0xF, true));
    x += __int_as_float(__builtin_amdgcn_update_dpp(0, __float_as_int(x), 0x141, 0xF, 0xF, true));
    x += __int_as_float(__builtin_amdgcn_update_dpp(0, __float_as_int(x), 0x140, 0xF, 0xF, true));
    return x;
}

// ---------------------------------------------------------------------------
// Kernel A (proven): pointwise parameter mapping.
// ---------------------------------------------------------------------------
__global__ __launch_bounds__(256) void shm_param_kernel(
    const float* __restrict__ xc, const float* __restrict__ lo,
    float* __restrict__ R, float* __restrict__ V)
{
    const int tid = blockIdx.x * 256 + threadIdx.x;
    const int m  = tid & 15;
    const int bt = tid >> 4;

    const float* lr = lo + (size_t)bt * 128 + m;
    const float r0 = lr[0],   r1 = lr[16],  r2 = lr[32],  r3 = lr[48];
    const float r4 = lr[64],  r5 = lr[80],  r6 = lr[96],  r7 = lr[112];

    const float* xp = xc + (size_t)bt * 3;
    const float prec = xp[0], pet = xp[1], temp = xp[2];
    const bool frozen = (temp < 0.f);
    const float tpos = frozen ? 0.f : temp;

    const float dd    = 10.f * sigmf(r0);
    const float sm    = tpos * dd;
    const float f_thr = fmaf(sigmf(r1), 50.f, 10.f);
    const float sumax = fmaf(sigmf(r2), 680.f, 20.f);
    const float beta  = fmaf(sigmf(r3), 5.f, 1.f);
    const float perc  = sigmf(r4);
    const float rkf   = rcpf(fmaf(sigmf(r5), 19.f, 1.f));
    const float rki   = rcpf(fmaf(sigmf(r6), 99.f, 1.f));
    const float rkb   = rcpf(fmaf(sigmf(r7), 990.f, 10.f));

    float4* Rp = (float4*)(R + (size_t)tid * 8);
    Rp[0] = make_float4(sm, f_thr, sumax, beta);
    Rp[1] = make_float4(perc, rkf, rki, rkb);
    if (m == 0)
        *(float4*)(V + (size_t)bt * 4) =
            make_float4(frozen ? prec : 0.f, frozen ? 0.f : prec, 0.9f * pet, 0.f);
}

// ---------------------------------------------------------------------------
// Kernel B: serial scan, LDS-DMA ring, SELF-CONTAINED 4-step regions.
// Region k: vmcnt(N) -> ds_read t=4k..4k+3 (current) -> lgkmcnt(0) ->
//           DMA-issue t=4k+15..4k+18 -> 4x STEPC.
// No registers cross a region boundary. Ledger: at region-k entry,
// issued = 45+12k loads, needed = 3*(4k+4) -> vmcnt(33) for k<=361;
// issuance ends at t=1459 -> tail fences 24 -> 12 -> 0.
// WAR: overwrites of this region's read slots (t=4k+16..18, same slots
// mod 16) are issued only AFTER this region's lgkmcnt(0).
// ---------------------------------------------------------------------------
__global__ __launch_bounds__(64, 1) void shm_serial_kernel(
    const float* __restrict__ R,
    const float* __restrict__ V,
    float* __restrict__ out)
{
    __shared__ __align__(16) char ring[RINGSZ];
    lds_c* ringc = (lds_c*)ring;
    const uint32_t ringB = (uint32_t)(uintptr_t)ringc;

    const int lane = threadIdx.x;
    const int m = lane & 15;
    const int b = (blockIdx.x * 64 + lane) >> 4;

    const float* pRd = R + ((size_t)b * T_LEN * 16 + m) * 8;   // +128 fl/step
    const float* pVd = V + (size_t)b * T_LEN * 4 + (lane & 3); // +4 fl/step
    float* op = out + (size_t)b * T_LEN;

    const uint32_t vbp = ringB + lane * 16;                  // param read base
    const uint32_t vbv = ringB + 2048 + ((lane & ~3) << 2);  // V read base
    uint32_t roff = 0;   // LDS offset of read-slot base (advances 4 slots)
    uint32_t woff = 0;   // LDS offset of next DMA slot (advances 1 slot)

    float ss = 0.f, sf = 1.f, su = 5.f, si = 10.f, sb = 15.f;
    float qkeep = 0.f;

    float4 XA0,XB0,XV0, XA1,XB1,XV1, XA2,XB2,XV2, XA3,XB3,XV3;

#define DMA16(gp, loff) __builtin_amdgcn_global_load_lds((g_c*)(gp), ringc + (loff), 16, 0, 0)
#define DMA4(gp, loff)  __builtin_amdgcn_global_load_lds((g_c*)(gp), ringc + (loff), 4, 0, 0)

#define ISSUE1(tt) { if ((tt) < T_LEN) {                                     \
    DMA16(pRd,     woff);                                                    \
    DMA16(pRd + 4, woff + 1024);                                             \
    DMA4 (pVd,     woff + 2048);                                             \
    pRd += 128; pVd += 4;                                                    \
    woff += RSLOT; woff = (woff == RINGSZ) ? 0u : woff; } }

#define RD3(DA, DB, DV, ap, av, OP1, OP2, OV)                                \
    asm volatile("ds_read_b128 %0, %3 offset:" OP1 "\n\t"                    \
                 "ds_read_b128 %1, %3 offset:" OP2 "\n\t"                    \
                 "ds_read_b128 %2, %4 offset:" OV                            \
                 : "=&v"(DA), "=&v"(DB), "=&v"(DV) : "v"(ap), "v"(av));

#define READ4() {                                                            \
    uint32_t ap = vbp + roff;                                                \
    uint32_t av = vbv + roff;                                                \
    RD3(XA0, XB0, XV0, ap, av, "0",    "1024", "0")                          \
    RD3(XA1, XB1, XV1, ap, av, "2304", "3328", "2304")                       \
    RD3(XA2, XB2, XV2, ap, av, "4608", "5632", "4608")                       \
    RD3(XA3, XB3, XV3, ap, av, "6912", "7936", "6912")                       \
    roff += 4 * RSLOT; roff = (roff == RINGSZ) ? 0u : roff; }

#define STEPC(j, tt) {                                                       \
    const float smv = XA##j.x, f_thr = XA##j.y, sumax = XA##j.z,             \
                beta = XA##j.w;                                              \
    const float perc = XB##j.x, rkf = XB##j.y, rki = XB##j.z,                \
                rkb = XB##j.w;                                               \
    const float et09 = XV##j.z;                                              \
    const float inv = rcpf(sumax);                                           \
    const float pwp = 0.8f * sumax;                                          \
    const float e_i = et09 * inv;                                            \
    const float qs_out = fminf(ss, smv);                                     \
    ss = (ss - qs_out) + XV##j.x;                                            \
    const float qsp = qs_out + XV##j.y;                                      \
    const float qf_in = fmaxf(0.f, qsp - f_thr);                             \
    const float qu_in = fminf(qsp, f_thr);                                   \
    sf += qf_in; const float qf_out = sf * rkf; sf -= qf_out;                \
    const float u = su * inv;                                                \
    const float psi = __builtin_amdgcn_exp2f(beta * __builtin_amdgcn_logf(u)); \
    const float su_t = fmaf(qu_in, 1.f - psi, su);                           \
    const float su2 = fminf(su_t, sumax);                                    \
    const float ovf = fmaxf(0.f, su_t - sumax);                              \
    const float qu_out = fmaf(qu_in, psi, ovf);                              \
    const float ret = (su2 <= pwp) ? su2 * e_i : et09;                       \
    su = fmaxf(0.f, su2 - ret);                                              \
    const float qi_in = qu_out * perc;                                       \
    si += qi_in; const float qi_out = si * rki; si -= qi_out;                \
    const float qb_in = qu_out - qi_in;                                      \
    sb += qb_in; const float qb_out = sb * rkb; sb -= qb_out;                \
    const float q = row_sum16(qf_out + qi_out + qb_out) * 0.0625f;           \
    qkeep = (m == ((tt) & 15)) ? q : qkeep;                                  \
    if (((tt) & 15) == 15) op[((tt) & ~15) + m] = qkeep;                     \
}

#define REGION_W(k, WN) {                                                    \
    const int tbase = 4 * (k);                                               \
    asm volatile("s_waitcnt vmcnt(" WN ")" ::: "memory");                    \
    __builtin_amdgcn_sched_barrier(0);                                       \
    READ4()                                                                  \
    asm volatile("s_waitcnt lgkmcnt(0)" ::: "memory");                       \
    __builtin_amdgcn_sched_barrier(0);                                       \
    ISSUE1(tbase + 15) ISSUE1(tbase + 16)                                    \
    ISSUE1(tbase + 17) ISSUE1(tbase + 18)                                    \
    STEPC(0, tbase)     STEPC(1, tbase + 1)                                  \
    STEPC(2, tbase + 2) STEPC(3, tbase + 3)                                  \
}

    // prologue: issue slots 0..14 (45 loads in flight)
    for (int j = 0; j < 15; ++j) { ISSUE1(j) }

    // regions 0..361: uniform vmcnt(33) ledger (issued 45+12k, need 12k+12)
    for (int k = 0; k < 362; ++k) {
        REGION_W(k, "33")
    }
    // tail: issuance ended at t=1459 -> fences tighten
    REGION_W(362, "24")   // need t<=1451 landed: 4380-4356 = 24
    REGION_W(363, "12")   // need t<=1455 landed: 4380-4368 = 12
    REGION_W(364, "0")    // need everything landed

    if (m < 4) op[1456 + m] = qkeep;   // t = 1456..1459 (held by m=0..3)

#undef DMA16
#undef DMA4
#undef ISSUE1
#undef RD3
#undef READ4
#undef STEPC
#undef REGION_W
}

// ---------------------------------------------------------------------------
// Fallback (proven round-2 kernel) if ws_size is too small.
// ---------------------------------------------------------------------------
#define CS 10
#define NCHUNK 146
#define IST 66

__device__ __forceinline__ float lane0f(float x) {
    return __int_as_float(__builtin_amdgcn_readlane(__float_as_int(x), 0));
}

__global__ __launch_bounds__(256, 1) void shm_pc_kernel(
    const float* __restrict__ xc, const float* __restrict__ lo,
    float* __restrict__ out)
{
    __shared__ float pbuf[2][CS][8][IST];
    __shared__ float bbuf[2][CS][4][4];

    const int lane  = threadIdx.x & 63;
    const int wid   = threadIdx.x >> 6;
    const int bbase = blockIdx.x * 4;

    const int ip = lane >> 3;
    const float A  = (ip==1)?10.f : (ip==2)?20.f : (ip==3)?1.f :
                     (ip==5)?1.f  : (ip==6)?1.f  : (ip==7)?10.f : 0.f;
    const float Bc = (ip==0)?10.f : (ip==1)?50.f : (ip==2)?680.f : (ip==3)?5.f :
                     (ip==4)?1.f  : (ip==5)?19.f : (ip==6)?99.f  : 990.f;
    const bool drcp = (ip >= 5);
    const bool dsm  = (ip == 0);
    const int  mm   = (2*lane) & 15;

    auto produce = [&](int cc, int buf) {
        const int t0 = cc * CS;
        float2 raw[14];
        float xr0[14], xr1[14], xr2[14];
#pragma unroll
        for (int r = 0; r < 14; ++r) {
            const int tau = (wid - 1) + 3 * r;
            if (tau < 40) {
                const int g  = tau / CS;
                const int tl = tau - g * CS;
                const size_t rowoff = (size_t)(bbase + g) * T_LEN + (t0 + tl);
                raw[r] = *(const float2*)(lo + rowoff * 128 + 2 * lane);
                if (lane == 0) {
                    const float* xp = xc + rowoff * 3;
                    xr0[r] = xp[0]; xr1[r] = xp[1]; xr2[r] = xp[2];
                }
            }
        }
#pragma unroll
        for (int r = 0; r < 14; ++r) {
            const int tau = (wid - 1) + 3 * r;
            if (tau < 40) {
                const int g  = tau / CS;
                const int tl = tau - g * CS;
                const float prec = lane0f(xr0[r]);
                const float pet  = lane0f(xr1[r]);
                const float temp = lane0f(xr2[r]);
                const bool frozen = (temp < 0.f);
                const float tpos = frozen ? 0.f : temp;
                const float sn   = frozen ? prec : 0.f;
                const float lpq  = frozen ? 0.f : prec;
                const float et09 = 0.9f * pet;

                float v0 = fmaf(sigmf(raw[r].x), Bc, A);
                float v1 = fmaf(sigmf(raw[r].y), Bc, A);
                v0 = drcp ? rcpf(v0) : v0;
                v1 = drcp ? rcpf(v1) : v1;
                v0 = dsm ? v0 * tpos : v0;
                v1 = dsm ? v1 * tpos : v1;

                float* dst = &pbuf[buf][tl][ip][g * 16 + mm];
                *(float2*)dst = make_float2(v0, v1);
                if (lane == 0)
                    *(float4*)&bbuf[buf][tl][g][0] = make_float4(sn, lpq, et09, 0.f);
            }
        }
    };

    const int g = lane >> 4, m = lane & 15;
    float ss = 0.f, sf = 1.f, su = 5.f, si = 10.f, sb = 15.f;
    float* op = out + (size_t)(bbase + g) * T_LEN;

    if (wid != 0) produce(0, 0);
    __syncthreads();

    for (int c = 0; c < NCHUNK; ++c) {
        if (wid == 0) {
            const int buf = c & 1;
#pragma unroll
            for (int tl = 0; tl < CS; ++tl) {
                const float* rec = &pbuf[buf][tl][0][lane];
                const float sm    = rec[0 * IST];
                const float f_thr = rec[1 * IST];
                const float sumax = rec[2 * IST];
                const float beta  = rec[3 * IST];
                const float perc  = rec[4 * IST];
                const float rkf   = rec[5 * IST];
                const float rki   = rec[6 * IST];
                const float rkb   = rec[7 * IST];
                const float4 bx = *(const float4*)&bbuf[buf][tl][g][0];

                float qs_out = fminf(ss, sm);
                ss = ss - qs_out + bx.x;
                float qsp = qs_out + bx.y;
                float qf_in = fmaxf(0.f, qsp - f_thr);
                float qu_in = fminf(qsp, f_thr);
                sf += qf_in;
                float qf_out = sf * rkf;
                sf -= qf_out;
                float inv_sumax = rcpf(sumax);
                float u = su * inv_sumax;
                float psi = __builtin_amdgcn_exp2f(beta * __builtin_amdgcn_logf(u));
                float su_temp = fmaf(qu_in, 1.f - psi, su);
                su = fminf(su_temp, sumax);
                float ovf = fmaxf(0.f, su_temp - sumax);
                float qu_out = fmaf(qu_in, psi, ovf);
                float pwp = 0.8f * sumax;
                float ktheta = (su <= pwp) ? su * inv_sumax : 1.f;
                float ret = bx.z * ktheta;
                su = fmaxf(0.f, su - ret);
                float qi_in = qu_out * perc;
                si += qi_in;
                float qi_out = si * rki;
                si -= qi_out;
                float qb_in = qu_out - qi_in;
                sb += qb_in;
                float qb_out = sb * rkb;
                sb -= qb_out;

                float q = row_sum16(qf_out + qi_out + qb_out) * 0.0625f;
                if (m == 0) op[c * CS + tl] = q;
            }
        } else if (c + 1 < NCHUNK) {
            produce(c + 1, (c + 1) & 1);
        }
        __syncthreads();
    }
}

extern "C" void kernel_launch(void* const* d_in, const int* in_sizes, int n_in,
                              void* d_out, int out_size, void* d_ws, size_t ws_size,
                              hipStream_t stream) {
    const float* xc = (const float*)d_in[0];   // [256,1460,3]
    const float* lo = (const float*)d_in[1];   // [256,1460,128]
    float* out = (float*)d_out;                // [256,1460,1]

    const size_t R_BYTES = (size_t)NREC * 32;  // 191,365,120
    const size_t V_BYTES = (size_t)NBT * 16;   //   5,980,160

    if (ws_size >= R_BYTES + V_BYTES) {
        float* R = (float*)d_ws;
        float* V = (float*)((char*)d_ws + R_BYTES);
        shm_param_kernel<<<dim3(NREC / 256), dim3(256), 0, stream>>>(xc, lo, R, V);
        shm_serial_kernel<<<dim3(64), dim3(64), 0, stream>>>(R, V, out);
    } else {
        shm_pc_kernel<<<dim3(64), dim3(256), 0, stream>>>(xc, lo, out);
    }
}